// Round 12
// baseline (95.616 us; speedup 1.0000x reference)
//
#include <hip/hip_runtime.h>
#include <hip/hip_bf16.h>
#include <math.h>

// Problem constants
#define S 64
#define F 10
#define K 7
#define D 512
#define HH 196   // H*H = 14*14
#define DT 128
#define NF (S*F)          // 640
#define NROWS_V (S*F*K)   // 4480
#define NROWS_A (S*K)     // 448
#define NOUT (S*K*F)      // 4480
#define MLP_R 16
#define MLP_TPB 128
#define NA_BLK (NROWS_A / MLP_R)   // 28
#define NV_BLK (NROWS_V / MLP_R)   // 280
#define WT 32                      // d-rows per staged W tile
#define WTILE_F4 (WT * DT / 4)     // 1024 float4 = 16 KB

typedef short bf16x8 __attribute__((ext_vector_type(8)));
typedef float f32x4 __attribute__((ext_vector_type(4)));

// f32 -> bf16 bits via the standard conversion (compiler emits native
// v_cvt[_pk]_bf16_f32 on gfx950 -- ~4x fewer VALU ops than a manual
// round-to-nearest-even bit sequence).
__device__ __forceinline__ short bfc(float x) {
  __hip_bfloat16 h = __float2bfloat16(x);
  return *reinterpret_cast<short*>(&h);
}

// ---------------------------------------------------------------------------
// Kernel 1 (v9, MFMA): per n: C[512x7] = feat[512x196] x cam^T[196x7] via
// mfma_f32_16x16x32_bf16 (K padded to 224, N padded to 16). A and B use the
// same elem->k convention; C/D col=lane&15 (class), row=(lane>>4)*4+i
// [m89-verified]. 1280 blocks x 4 independent waves; no LDS/barriers/shuffles
// in the hot loop. Only change vs R11: bfr -> bfc (native cvt).
// ---------------------------------------------------------------------------
__global__ __launch_bounds__(256) void fg_kernel(
    const float* __restrict__ feat, const float* __restrict__ cam,
    float* __restrict__ fg) {
  const int t = threadIdx.x;
  const int lane = t & 63;
  const int w = t >> 6;
  const int col = lane & 15;
  const int kg = lane >> 4;
  const int n = blockIdx.x >> 1;
  const int half = blockIdx.x & 1;
  const int c0blk = half * 256;

  const float* featn = feat + ((size_t)n * D + c0blk) * HH;
  const float* camn = cam + (size_t)n * K * HH;

  // ---- B fragments (cam, bf16) for 7 k-slabs ----
  bf16x8 bs[7];
  {
    const float* crow = camn + col * HH;
#pragma unroll
    for (int s = 0; s < 7; ++s) {
      float v0 = 0.f, v1 = 0.f, v2 = 0.f, v3 = 0.f;
      float v4 = 0.f, v5 = 0.f, v6 = 0.f, v7 = 0.f;
      if (col < 7) {
        if (s < 6) {
          const float4 lo = *reinterpret_cast<const float4*>(crow + s * 32 + kg * 8);
          const float4 hi = *reinterpret_cast<const float4*>(crow + s * 32 + kg * 8 + 4);
          v0 = lo.x; v1 = lo.y; v2 = lo.z; v3 = lo.w;
          v4 = hi.x; v5 = hi.y; v6 = hi.z; v7 = hi.w;
        } else if (kg == 0) {
          const float4 lo = *reinterpret_cast<const float4*>(crow + 192);
          v0 = lo.x; v1 = lo.y; v2 = lo.z; v3 = lo.w;
        }
      }
      bs[s][0] = bfc(v0); bs[s][1] = bfc(v1); bs[s][2] = bfc(v2); bs[s][3] = bfc(v3);
      bs[s][4] = bfc(v4); bs[s][5] = bfc(v5); bs[s][6] = bfc(v6); bs[s][7] = bfc(v7);
    }
  }

  // ---- inv[col] via per-wave butterflies ----
  float invc = 0.f;
#pragma unroll
  for (int k = 0; k < K; ++k) {
    float4 cv = (lane < 49)
                    ? *reinterpret_cast<const float4*>(camn + k * HH + 4 * lane)
                    : make_float4(0.f, 0.f, 0.f, 0.f);
    float s = cv.x + cv.y + cv.z + cv.w;
#pragma unroll
    for (int m = 32; m >= 1; m >>= 1) s += __shfl_xor(s, m, 64);
    const float iv = 1.0f / (s + 1e-10f);
    if (col == k) invc = iv;
  }

  float* fgn = fg + (size_t)n * K * D;

#pragma unroll
  for (int mt = 0; mt < 4; ++mt) {
    const int chl = (w * 4 + mt) * 16 + col;
    const float* rowp = featn + (size_t)chl * HH;

    f32x4 acc = {0.f, 0.f, 0.f, 0.f};
#pragma unroll
    for (int s = 0; s < 7; ++s) {
      float v0 = 0.f, v1 = 0.f, v2 = 0.f, v3 = 0.f;
      float v4 = 0.f, v5 = 0.f, v6 = 0.f, v7 = 0.f;
      if (s < 6) {
        const float4 lo = *reinterpret_cast<const float4*>(rowp + s * 32 + kg * 8);
        const float4 hi = *reinterpret_cast<const float4*>(rowp + s * 32 + kg * 8 + 4);
        v0 = lo.x; v1 = lo.y; v2 = lo.z; v3 = lo.w;
        v4 = hi.x; v5 = hi.y; v6 = hi.z; v7 = hi.w;
      } else if (kg == 0) {
        const float4 lo = *reinterpret_cast<const float4*>(rowp + 192);
        v0 = lo.x; v1 = lo.y; v2 = lo.z; v3 = lo.w;
      }
      bf16x8 a;
      a[0] = bfc(v0); a[1] = bfc(v1); a[2] = bfc(v2); a[3] = bfc(v3);
      a[4] = bfc(v4); a[5] = bfc(v5); a[6] = bfc(v6); a[7] = bfc(v7);
      acc = __builtin_amdgcn_mfma_f32_16x16x32_bf16(a, bs[s], acc, 0, 0, 0);
    }

    if (col < 7) {
      float4 o;
      o.x = acc[0] * invc; o.y = acc[1] * invc;
      o.z = acc[2] * invc; o.w = acc[3] * invc;
      *reinterpret_cast<float4*>(
          fgn + (size_t)col * D + c0blk + (w * 4 + mt) * 16 + kg * 4) = o;
    }
  }
}

// ---------------------------------------------------------------------------
// Kernel 2 (v6): BOTH MLPs. 16 rows/block x 128 thr; thread = 4 rows x 4
// cols -> each W ds_read_b128 feeds 16 FMAs (4x less DS-pipe than v5).
// W double-buffered via global_load_lds (32 KB); hs 8 KB; LDS 40 KB ->
// 4 blocks/CU co-resident. 308 blocks.
// ---------------------------------------------------------------------------
__device__ __forceinline__ void fma4(float4& acc, float sx, const float4& wv) {
  acc.x += sx * wv.x; acc.y += sx * wv.y; acc.z += sx * wv.z; acc.w += sx * wv.w;
}

__device__ __forceinline__ void stage_w(const float* src, float4* dst, int t) {
#pragma unroll
  for (int i = 0; i < WTILE_F4; i += MLP_TPB) {
    __builtin_amdgcn_global_load_lds(
        (const __attribute__((address_space(1))) void*)(src + (size_t)(i + t) * 4),
        (__attribute__((address_space(3))) void*)(dst + i + t), 16, 0, 0);
  }
}

__global__ __launch_bounds__(MLP_TPB) void mlp2_kernel(
    const float* __restrict__ Xa, const float* __restrict__ Xv,
    const float* __restrict__ W1a, const float* __restrict__ b1a,
    const float* __restrict__ W2a, const float* __restrict__ b2a,
    const float* __restrict__ ga, const float* __restrict__ bna,
    const float* __restrict__ W1v, const float* __restrict__ b1v,
    const float* __restrict__ W2v, const float* __restrict__ b2v,
    const float* __restrict__ gv, const float* __restrict__ bnv,
    float* __restrict__ Ta, float* __restrict__ Tv) {
  __shared__ float4 wbuf[2][WTILE_F4];   // 32 KB
  __shared__ float hs[MLP_R * DT];       // 8 KB
  const int t = threadIdx.x;
  const int b = blockIdx.x;

  const float *X, *W1, *b1, *W2, *b2, *g, *bn;
  float* out;
  int r0;
  if (b < NA_BLK) {
    X = Xa; W1 = W1a; b1 = b1a; W2 = W2a; b2 = b2a; g = ga; bn = bna;
    out = Ta; r0 = b * MLP_R;
  } else {
    X = Xv; W1 = W1v; b1 = b1v; W2 = W2v; b2 = b2v; g = gv; bn = bnv;
    out = Tv; r0 = (b - NA_BLK) * MLP_R;
  }

  const int cg = t & 31;   // col group -> j0 = cg*4
  const int j0 = cg * 4;
  const int rq = t >> 5;   // 0..3 -> rows rq, rq+4, rq+8, rq+12

  const float4* xr0 = reinterpret_cast<const float4*>(X + (size_t)(r0 + rq) * D);
  const float4* xr1 = reinterpret_cast<const float4*>(X + (size_t)(r0 + rq + 4) * D);
  const float4* xr2 = reinterpret_cast<const float4*>(X + (size_t)(r0 + rq + 8) * D);
  const float4* xr3 = reinterpret_cast<const float4*>(X + (size_t)(r0 + rq + 12) * D);

  stage_w(W1, &wbuf[0][0], t);
  __syncthreads();

  // ---- layer 1: 16 tiles of 32 d-rows ----
  float4 a0 = *reinterpret_cast<const float4*>(b1 + j0);
  float4 a1 = a0, a2 = a0, a3 = a0;
  for (int dt = 0; dt < 16; ++dt) {
    if (dt < 15) stage_w(W1 + (size_t)(dt + 1) * WT * DT, &wbuf[(dt + 1) & 1][0], t);
    else         stage_w(W2, &wbuf[0][0], t);  // prefetch W2 tile 0
    const float4* wb = &wbuf[dt & 1][0];
#pragma unroll
    for (int d4 = 0; d4 < 8; ++d4) {
      const float4 x0 = xr0[dt * 8 + d4];
      const float4 x1 = xr1[dt * 8 + d4];
      const float4 x2 = xr2[dt * 8 + d4];
      const float4 x3 = xr3[dt * 8 + d4];
      const float4 w0 = wb[(d4 * 4 + 0) * 32 + cg];
      const float4 w1 = wb[(d4 * 4 + 1) * 32 + cg];
      const float4 w2 = wb[(d4 * 4 + 2) * 32 + cg];
      const float4 w3 = wb[(d4 * 4 + 3) * 32 + cg];
      fma4(a0, x0.x, w0); fma4(a0, x0.y, w1); fma4(a0, x0.z, w2); fma4(a0, x0.w, w3);
      fma4(a1, x1.x, w0); fma4(a1, x1.y, w1); fma4(a1, x1.z, w2); fma4(a1, x1.w, w3);
      fma4(a2, x2.x, w0); fma4(a2, x2.y, w1); fma4(a2, x2.z, w2); fma4(a2, x2.w, w3);
      fma4(a3, x3.x, w0); fma4(a3, x3.y, w1); fma4(a3, x3.z, w2); fma4(a3, x3.w, w3);
    }
    __syncthreads();  // stage landed; all waves done with wbuf[dt&1]
  }

  // relu -> hs (4 rows)
  a0.x = fmaxf(a0.x, 0.f); a0.y = fmaxf(a0.y, 0.f); a0.z = fmaxf(a0.z, 0.f); a0.w = fmaxf(a0.w, 0.f);
  a1.x = fmaxf(a1.x, 0.f); a1.y = fmaxf(a1.y, 0.f); a1.z = fmaxf(a1.z, 0.f); a1.w = fmaxf(a1.w, 0.f);
  a2.x = fmaxf(a2.x, 0.f); a2.y = fmaxf(a2.y, 0.f); a2.z = fmaxf(a2.z, 0.f); a2.w = fmaxf(a2.w, 0.f);
  a3.x = fmaxf(a3.x, 0.f); a3.y = fmaxf(a3.y, 0.f); a3.z = fmaxf(a3.z, 0.f); a3.w = fmaxf(a3.w, 0.f);
  *reinterpret_cast<float4*>(hs + (rq) * DT + j0) = a0;
  *reinterpret_cast<float4*>(hs + (rq + 4) * DT + j0) = a1;
  *reinterpret_cast<float4*>(hs + (rq + 8) * DT + j0) = a2;
  *reinterpret_cast<float4*>(hs + (rq + 12) * DT + j0) = a3;
  __syncthreads();  // hs published (W2 tile 0 landed at loop-end barrier)

  const float4* h0 = reinterpret_cast<const float4*>(hs + (rq) * DT);
  const float4* h1 = reinterpret_cast<const float4*>(hs + (rq + 4) * DT);
  const float4* h2 = reinterpret_cast<const float4*>(hs + (rq + 8) * DT);
  const float4* h3 = reinterpret_cast<const float4*>(hs + (rq + 12) * DT);

  // ---- layer 2: 4 tiles ----
  float4 c0 = *reinterpret_cast<const float4*>(b2 + j0);
  float4 c1 = c0, c2 = c0, c3 = c0;
  for (int dt = 0; dt < 4; ++dt) {
    if (dt < 3) stage_w(W2 + (size_t)(dt + 1) * WT * DT, &wbuf[(dt + 1) & 1][0], t);
    const float4* wb = &wbuf[dt & 1][0];
#pragma unroll
    for (int d4 = 0; d4 < 8; ++d4) {
      const float4 x0 = h0[dt * 8 + d4];
      const float4 x1 = h1[dt * 8 + d4];
      const float4 x2 = h2[dt * 8 + d4];
      const float4 x3 = h3[dt * 8 + d4];
      const float4 w0 = wb[(d4 * 4 + 0) * 32 + cg];
      const float4 w1 = wb[(d4 * 4 + 1) * 32 + cg];
      const float4 w2 = wb[(d4 * 4 + 2) * 32 + cg];
      const float4 w3 = wb[(d4 * 4 + 3) * 32 + cg];
      fma4(c0, x0.x, w0); fma4(c0, x0.y, w1); fma4(c0, x0.z, w2); fma4(c0, x0.w, w3);
      fma4(c1, x1.x, w0); fma4(c1, x1.y, w1); fma4(c1, x1.z, w2); fma4(c1, x1.w, w3);
      fma4(c2, x2.x, w0); fma4(c2, x2.y, w1); fma4(c2, x2.z, w2); fma4(c2, x2.w, w3);
      fma4(c3, x3.x, w0); fma4(c3, x3.y, w1); fma4(c3, x3.z, w2); fma4(c3, x3.w, w3);
    }
    __syncthreads();
  }

  // affine epilogue
  const float4 gvv = *reinterpret_cast<const float4*>(g + j0);
  const float4 bv = *reinterpret_cast<const float4*>(bn + j0);
  float4 o;
  o.x = c0.x * gvv.x + bv.x; o.y = c0.y * gvv.y + bv.y;
  o.z = c0.z * gvv.z + bv.z; o.w = c0.w * gvv.w + bv.w;
  *reinterpret_cast<float4*>(out + (size_t)(r0 + rq) * DT + j0) = o;
  o.x = c1.x * gvv.x + bv.x; o.y = c1.y * gvv.y + bv.y;
  o.z = c1.z * gvv.z + bv.z; o.w = c1.w * gvv.w + bv.w;
  *reinterpret_cast<float4*>(out + (size_t)(r0 + rq + 4) * DT + j0) = o;
  o.x = c2.x * gvv.x + bv.x; o.y = c2.y * gvv.y + bv.y;
  o.z = c2.z * gvv.z + bv.z; o.w = c2.w * gvv.w + bv.w;
  *reinterpret_cast<float4*>(out + (size_t)(r0 + rq + 8) * DT + j0) = o;
  o.x = c3.x * gvv.x + bv.x; o.y = c3.y * gvv.y + bv.y;
  o.z = c3.z * gvv.z + bv.z; o.w = c3.w * gvv.w + bv.w;
  *reinterpret_cast<float4*>(out + (size_t)(r0 + rq + 12) * DT + j0) = o;
}

// ---------------------------------------------------------------------------
// Kernel 3: losses + masks (unchanged; ~0.85 us).
// ---------------------------------------------------------------------------
__global__ __launch_bounds__(256) void loss_kernel(
    const float* __restrict__ Ta, const float* __restrict__ Tv,
    const float* __restrict__ pred_a, const float* __restrict__ pred_v,
    const int* __restrict__ perm_idx, const int* __restrict__ cls_idx,
    float* __restrict__ out) {
  const int t = threadIdx.x;
  const int sub = t & 31;
  const int idx = blockIdx.x * 8 + (t >> 5);
  const int f = idx % F;
  const int k = (idx / F) % K;
  const int s = idx / (K * F);

  const int p = perm_idx[idx];
  const int c = cls_idx[idx];
  const int rowd = ((s ^ 1) * F + p) * K + c;

  float4 ta = reinterpret_cast<const float4*>(Ta)[(s * K + k) * 32 + sub];
  float4 tv = reinterpret_cast<const float4*>(Tv)[((s * F + f) * K + k) * 32 + sub];
  float4 td = reinterpret_cast<const float4*>(Tv)[rowd * 32 + sub];
  float d1 = 0.f, d2 = 0.f, e;
  e = ta.x - tv.x; d1 += e * e;
  e = ta.y - tv.y; d1 += e * e;
  e = ta.z - tv.z; d1 += e * e;
  e = ta.w - tv.w; d1 += e * e;
  e = ta.x - td.x; d2 += e * e;
  e = ta.y - td.y; d2 += e * e;
  e = ta.z - td.z; d2 += e * e;
  e = ta.w - td.w; d2 += e * e;
#pragma unroll
  for (int m = 16; m >= 1; m >>= 1) {
    d1 += __shfl_xor(d1, m, 64);
    d2 += __shfl_xor(d2, m, 64);
  }
  if (sub == 0) {
    float pa = pred_a[s * K + k];
    bool act = pa > 0.3f;
    int num = (int)floorf(pa * (float)F);
    float pvv = pred_v[(s * F + f) * K + k];
    float sg = 1.0f / (1.0f + expf(-pvv));
    bool mco = act && (sg > 0.3f);
    bool mdi = act && (f < num);
    float lco = d1 * (1.0f / 128.0f);
    float ldi = d2 * (1.0f / 128.0f);
    out[idx] = mco ? lco : 0.0f;
    out[NOUT + idx] = mdi ? ldi : 0.0f;
    out[2 * NOUT + idx] = mco ? 1.0f : 0.0f;
    out[3 * NOUT + idx] = mdi ? 1.0f : 0.0f;
  }
}

extern "C" void kernel_launch(void* const* d_in, const int* in_sizes, int n_in,
                              void* d_out, int out_size, void* d_ws, size_t ws_size,
                              hipStream_t stream) {
  const float* feat_a     = (const float*)d_in[0];
  const float* pred_a     = (const float*)d_in[1];
  const float* feat_v_raw = (const float*)d_in[2];
  const float* pred_v     = (const float*)d_in[3];
  const float* cam        = (const float*)d_in[4];
  const float* W1a = (const float*)d_in[5];
  const float* b1a = (const float*)d_in[6];
  const float* W2a = (const float*)d_in[7];
  const float* b2a = (const float*)d_in[8];
  const float* ga  = (const float*)d_in[9];
  const float* bna = (const float*)d_in[10];
  const float* W1v = (const float*)d_in[11];
  const float* b1v = (const float*)d_in[12];
  const float* W2v = (const float*)d_in[13];
  const float* b2v = (const float*)d_in[14];
  const float* gv  = (const float*)d_in[15];
  const float* bnv = (const float*)d_in[16];
  const int* perm_idx = (const int*)d_in[17];
  const int* cls_idx  = (const int*)d_in[18];
  float* out = (float*)d_out;

  // workspace layout (floats): fg[640*7*512] | Ta[448*128] | Tv[4480*128]
  float* ws = (float*)d_ws;
  float* fg = ws;
  float* Ta = fg + (size_t)NF * K * D;
  float* Tv = Ta + (size_t)NROWS_A * DT;

  fg_kernel<<<NF * 2, 256, 0, stream>>>(feat_v_raw, cam, fg);
  mlp2_kernel<<<NA_BLK + NV_BLK, MLP_TPB, 0, stream>>>(
      feat_a, fg, W1a, b1a, W2a, b2a, ga, bna,
      W1v, b1v, W2v, b2v, gv, bnv, Ta, Tv);
  loss_kernel<<<NOUT / 8, 256, 0, stream>>>(Ta, Tv, pred_a, pred_v, perm_idx,
                                            cls_idx, out);
}

// Round 13
// 82.525 us; speedup vs baseline: 1.1586x; 1.1586x over previous
//
#include <hip/hip_runtime.h>
#include <hip/hip_bf16.h>
#include <math.h>

// Problem constants
#define S 64
#define F 10
#define K 7
#define D 512
#define HH 196   // H*H = 14*14
#define DT 128
#define NF (S*F)          // 640
#define NROWS_V (S*F*K)   // 4480
#define NROWS_A (S*K)     // 448
#define NOUT (S*K*F)      // 4480
#define MLP_R 8
#define NA_BLK (NROWS_A / MLP_R)   // 56
#define NV_BLK (NROWS_V / MLP_R)   // 560
#define WT 32                      // d-rows per staged W tile
#define WTILE_F4 (WT * DT / 4)     // 1024 float4 = 16 KB

typedef short bf16x8 __attribute__((ext_vector_type(8)));
typedef float f32x4 __attribute__((ext_vector_type(4)));

// f32 -> bf16 via native cvt (single remaining delta vs the 85.2us R11 config)
__device__ __forceinline__ short bfc(float x) {
  __hip_bfloat16 h = __float2bfloat16(x);
  return *reinterpret_cast<short*>(&h);
}

// ---------------------------------------------------------------------------
// Kernel 1 (v9, MFMA): per n: C[512x7] = feat[512x196] x cam^T[196x7] via
// mfma_f32_16x16x32_bf16 (K padded 224, N padded 16). A/B share the elem->k
// convention; C/D col=lane&15, row=(lane>>4)*4+i [m89-verified]. 1280 blocks
// (5/CU exactly) x 4 independent waves; no LDS/barriers in the hot loop.
// ---------------------------------------------------------------------------
__global__ __launch_bounds__(256) void fg_kernel(
    const float* __restrict__ feat, const float* __restrict__ cam,
    float* __restrict__ fg) {
  const int t = threadIdx.x;
  const int lane = t & 63;
  const int w = t >> 6;
  const int col = lane & 15;
  const int kg = lane >> 4;
  const int n = blockIdx.x >> 1;
  const int half = blockIdx.x & 1;
  const int c0blk = half * 256;

  const float* featn = feat + ((size_t)n * D + c0blk) * HH;
  const float* camn = cam + (size_t)n * K * HH;

  // ---- B fragments (cam, bf16) for 7 k-slabs ----
  bf16x8 bs[7];
  {
    const float* crow = camn + col * HH;
#pragma unroll
    for (int s = 0; s < 7; ++s) {
      float v0 = 0.f, v1 = 0.f, v2 = 0.f, v3 = 0.f;
      float v4 = 0.f, v5 = 0.f, v6 = 0.f, v7 = 0.f;
      if (col < 7) {
        if (s < 6) {
          const float4 lo = *reinterpret_cast<const float4*>(crow + s * 32 + kg * 8);
          const float4 hi = *reinterpret_cast<const float4*>(crow + s * 32 + kg * 8 + 4);
          v0 = lo.x; v1 = lo.y; v2 = lo.z; v3 = lo.w;
          v4 = hi.x; v5 = hi.y; v6 = hi.z; v7 = hi.w;
        } else if (kg == 0) {
          const float4 lo = *reinterpret_cast<const float4*>(crow + 192);
          v0 = lo.x; v1 = lo.y; v2 = lo.z; v3 = lo.w;
        }
      }
      bs[s][0] = bfc(v0); bs[s][1] = bfc(v1); bs[s][2] = bfc(v2); bs[s][3] = bfc(v3);
      bs[s][4] = bfc(v4); bs[s][5] = bfc(v5); bs[s][6] = bfc(v6); bs[s][7] = bfc(v7);
    }
  }

  // ---- inv[col] via per-wave butterflies ----
  float invc = 0.f;
#pragma unroll
  for (int k = 0; k < K; ++k) {
    float4 cv = (lane < 49)
                    ? *reinterpret_cast<const float4*>(camn + k * HH + 4 * lane)
                    : make_float4(0.f, 0.f, 0.f, 0.f);
    float s = cv.x + cv.y + cv.z + cv.w;
#pragma unroll
    for (int m = 32; m >= 1; m >>= 1) s += __shfl_xor(s, m, 64);
    const float iv = 1.0f / (s + 1e-10f);
    if (col == k) invc = iv;
  }

  float* fgn = fg + (size_t)n * K * D;

#pragma unroll
  for (int mt = 0; mt < 4; ++mt) {
    const int chl = (w * 4 + mt) * 16 + col;
    const float* rowp = featn + (size_t)chl * HH;

    f32x4 acc = {0.f, 0.f, 0.f, 0.f};
#pragma unroll
    for (int s = 0; s < 7; ++s) {
      float v0 = 0.f, v1 = 0.f, v2 = 0.f, v3 = 0.f;
      float v4 = 0.f, v5 = 0.f, v6 = 0.f, v7 = 0.f;
      if (s < 6) {
        const float4 lo = *reinterpret_cast<const float4*>(rowp + s * 32 + kg * 8);
        const float4 hi = *reinterpret_cast<const float4*>(rowp + s * 32 + kg * 8 + 4);
        v0 = lo.x; v1 = lo.y; v2 = lo.z; v3 = lo.w;
        v4 = hi.x; v5 = hi.y; v6 = hi.z; v7 = hi.w;
      } else if (kg == 0) {
        const float4 lo = *reinterpret_cast<const float4*>(rowp + 192);
        v0 = lo.x; v1 = lo.y; v2 = lo.z; v3 = lo.w;
      }
      bf16x8 a;
      a[0] = bfc(v0); a[1] = bfc(v1); a[2] = bfc(v2); a[3] = bfc(v3);
      a[4] = bfc(v4); a[5] = bfc(v5); a[6] = bfc(v6); a[7] = bfc(v7);
      acc = __builtin_amdgcn_mfma_f32_16x16x32_bf16(a, bs[s], acc, 0, 0, 0);
    }

    if (col < 7) {
      float4 o;
      o.x = acc[0] * invc; o.y = acc[1] * invc;
      o.z = acc[2] * invc; o.w = acc[3] * invc;
      *reinterpret_cast<float4*>(
          fgn + (size_t)col * D + c0blk + (w * 4 + mt) * 16 + kg * 4) = o;
    }
  }
}

// ---------------------------------------------------------------------------
// Kernel 2 (v5 verbatim, R10/R11-proven ~19 us): BOTH MLPs. 8 rows/block x
// 256 thr (thread = 1 row x 4 cols) -> 616 blocks, 2464 waves. W double-
// buffered via global_load_lds; x from global (L1 broadcast).
// Occupancy > DS-count for this kernel (R12 lesson).
// ---------------------------------------------------------------------------
__device__ __forceinline__ void fma4(float4& acc, float sx, const float4& wv) {
  acc.x += sx * wv.x; acc.y += sx * wv.y; acc.z += sx * wv.z; acc.w += sx * wv.w;
}

__device__ __forceinline__ void stage_w(const float* src, float4* dst, int t) {
#pragma unroll
  for (int i = 0; i < WTILE_F4; i += 256) {
    __builtin_amdgcn_global_load_lds(
        (const __attribute__((address_space(1))) void*)(src + (size_t)(i + t) * 4),
        (__attribute__((address_space(3))) void*)(dst + i + t), 16, 0, 0);
  }
}

__global__ __launch_bounds__(256) void mlp2_kernel(
    const float* __restrict__ Xa, const float* __restrict__ Xv,
    const float* __restrict__ W1a, const float* __restrict__ b1a,
    const float* __restrict__ W2a, const float* __restrict__ b2a,
    const float* __restrict__ ga, const float* __restrict__ bna,
    const float* __restrict__ W1v, const float* __restrict__ b1v,
    const float* __restrict__ W2v, const float* __restrict__ b2v,
    const float* __restrict__ gv, const float* __restrict__ bnv,
    float* __restrict__ Ta, float* __restrict__ Tv) {
  __shared__ float4 wbuf[2][WTILE_F4];   // 32 KB
  __shared__ float hs[MLP_R * DT];       // 4 KB
  const int t = threadIdx.x;
  const int b = blockIdx.x;

  const float *X, *W1, *b1, *W2, *b2, *g, *bn;
  float* out;
  int r0;
  if (b < NA_BLK) {
    X = Xa; W1 = W1a; b1 = b1a; W2 = W2a; b2 = b2a; g = ga; bn = bna;
    out = Ta; r0 = b * MLP_R;
  } else {
    X = Xv; W1 = W1v; b1 = b1v; W2 = W2v; b2 = b2v; g = gv; bn = bnv;
    out = Tv; r0 = (b - NA_BLK) * MLP_R;
  }

  const int cg = t & 31;
  const int j0 = cg * 4;
  const int rp = t >> 5;
  const float4* xrow = reinterpret_cast<const float4*>(X + (size_t)(r0 + rp) * D);

  stage_w(W1, &wbuf[0][0], t);
  __syncthreads();

  // ---- layer 1: 16 tiles of 32 d-rows ----
  float4 a0 = *reinterpret_cast<const float4*>(b1 + j0);
  for (int dt = 0; dt < 16; ++dt) {
    if (dt < 15) stage_w(W1 + (size_t)(dt + 1) * WT * DT, &wbuf[(dt + 1) & 1][0], t);
    else         stage_w(W2, &wbuf[0][0], t);  // prefetch W2 tile 0
    const float4* wb = &wbuf[dt & 1][0];
#pragma unroll
    for (int d4 = 0; d4 < 8; ++d4) {
      const float4 x0 = xrow[dt * 8 + d4];
      const float4 w0 = wb[(d4 * 4 + 0) * 32 + cg];
      const float4 w1 = wb[(d4 * 4 + 1) * 32 + cg];
      const float4 w2 = wb[(d4 * 4 + 2) * 32 + cg];
      const float4 w3 = wb[(d4 * 4 + 3) * 32 + cg];
      fma4(a0, x0.x, w0); fma4(a0, x0.y, w1); fma4(a0, x0.z, w2); fma4(a0, x0.w, w3);
    }
    __syncthreads();
  }

  a0.x = fmaxf(a0.x, 0.f); a0.y = fmaxf(a0.y, 0.f);
  a0.z = fmaxf(a0.z, 0.f); a0.w = fmaxf(a0.w, 0.f);
  *reinterpret_cast<float4*>(hs + rp * DT + j0) = a0;
  __syncthreads();

  const float4* hrow = reinterpret_cast<const float4*>(hs + rp * DT);

  // ---- layer 2: 4 tiles ----
  float4 c0 = *reinterpret_cast<const float4*>(b2 + j0);
  for (int dt = 0; dt < 4; ++dt) {
    if (dt < 3) stage_w(W2 + (size_t)(dt + 1) * WT * DT, &wbuf[(dt + 1) & 1][0], t);
    const float4* wb = &wbuf[dt & 1][0];
#pragma unroll
    for (int d4 = 0; d4 < 8; ++d4) {
      const float4 x0 = hrow[dt * 8 + d4];
      const float4 w0 = wb[(d4 * 4 + 0) * 32 + cg];
      const float4 w1 = wb[(d4 * 4 + 1) * 32 + cg];
      const float4 w2 = wb[(d4 * 4 + 2) * 32 + cg];
      const float4 w3 = wb[(d4 * 4 + 3) * 32 + cg];
      fma4(c0, x0.x, w0); fma4(c0, x0.y, w1); fma4(c0, x0.z, w2); fma4(c0, x0.w, w3);
    }
    __syncthreads();
  }

  const float4 gvv = *reinterpret_cast<const float4*>(g + j0);
  const float4 bv = *reinterpret_cast<const float4*>(bn + j0);
  float4 o0;
  o0.x = c0.x * gvv.x + bv.x; o0.y = c0.y * gvv.y + bv.y;
  o0.z = c0.z * gvv.z + bv.z; o0.w = c0.w * gvv.w + bv.w;
  *reinterpret_cast<float4*>(out + (size_t)(r0 + rp) * DT + j0) = o0;
}

// ---------------------------------------------------------------------------
// Kernel 3: losses + masks (unchanged; ~0.85 us).
// ---------------------------------------------------------------------------
__global__ __launch_bounds__(256) void loss_kernel(
    const float* __restrict__ Ta, const float* __restrict__ Tv,
    const float* __restrict__ pred_a, const float* __restrict__ pred_v,
    const int* __restrict__ perm_idx, const int* __restrict__ cls_idx,
    float* __restrict__ out) {
  const int t = threadIdx.x;
  const int sub = t & 31;
  const int idx = blockIdx.x * 8 + (t >> 5);
  const int f = idx % F;
  const int k = (idx / F) % K;
  const int s = idx / (K * F);

  const int p = perm_idx[idx];
  const int c = cls_idx[idx];
  const int rowd = ((s ^ 1) * F + p) * K + c;

  float4 ta = reinterpret_cast<const float4*>(Ta)[(s * K + k) * 32 + sub];
  float4 tv = reinterpret_cast<const float4*>(Tv)[((s * F + f) * K + k) * 32 + sub];
  float4 td = reinterpret_cast<const float4*>(Tv)[rowd * 32 + sub];
  float d1 = 0.f, d2 = 0.f, e;
  e = ta.x - tv.x; d1 += e * e;
  e = ta.y - tv.y; d1 += e * e;
  e = ta.z - tv.z; d1 += e * e;
  e = ta.w - tv.w; d1 += e * e;
  e = ta.x - td.x; d2 += e * e;
  e = ta.y - td.y; d2 += e * e;
  e = ta.z - td.z; d2 += e * e;
  e = ta.w - td.w; d2 += e * e;
#pragma unroll
  for (int m = 16; m >= 1; m >>= 1) {
    d1 += __shfl_xor(d1, m, 64);
    d2 += __shfl_xor(d2, m, 64);
  }
  if (sub == 0) {
    float pa = pred_a[s * K + k];
    bool act = pa > 0.3f;
    int num = (int)floorf(pa * (float)F);
    float pvv = pred_v[(s * F + f) * K + k];
    float sg = 1.0f / (1.0f + expf(-pvv));
    bool mco = act && (sg > 0.3f);
    bool mdi = act && (f < num);
    float lco = d1 * (1.0f / 128.0f);
    float ldi = d2 * (1.0f / 128.0f);
    out[idx] = mco ? lco : 0.0f;
    out[NOUT + idx] = mdi ? ldi : 0.0f;
    out[2 * NOUT + idx] = mco ? 1.0f : 0.0f;
    out[3 * NOUT + idx] = mdi ? 1.0f : 0.0f;
  }
}

extern "C" void kernel_launch(void* const* d_in, const int* in_sizes, int n_in,
                              void* d_out, int out_size, void* d_ws, size_t ws_size,
                              hipStream_t stream) {
  const float* feat_a     = (const float*)d_in[0];
  const float* pred_a     = (const float*)d_in[1];
  const float* feat_v_raw = (const float*)d_in[2];
  const float* pred_v     = (const float*)d_in[3];
  const float* cam        = (const float*)d_in[4];
  const float* W1a = (const float*)d_in[5];
  const float* b1a = (const float*)d_in[6];
  const float* W2a = (const float*)d_in[7];
  const float* b2a = (const float*)d_in[8];
  const float* ga  = (const float*)d_in[9];
  const float* bna = (const float*)d_in[10];
  const float* W1v = (const float*)d_in[11];
  const float* b1v = (const float*)d_in[12];
  const float* W2v = (const float*)d_in[13];
  const float* b2v = (const float*)d_in[14];
  const float* gv  = (const float*)d_in[15];
  const float* bnv = (const float*)d_in[16];
  const int* perm_idx = (const int*)d_in[17];
  const int* cls_idx  = (const int*)d_in[18];
  float* out = (float*)d_out;

  // workspace layout (floats): fg[640*7*512] | Ta[448*128] | Tv[4480*128]
  float* ws = (float*)d_ws;
  float* fg = ws;
  float* Ta = fg + (size_t)NF * K * D;
  float* Tv = Ta + (size_t)NROWS_A * DT;

  fg_kernel<<<NF * 2, 256, 0, stream>>>(feat_v_raw, cam, fg);
  mlp2_kernel<<<NA_BLK + NV_BLK, 256, 0, stream>>>(
      feat_a, fg, W1a, b1a, W2a, b2a, ga, bna,
      W1v, b1v, W2v, b2v, gv, bnv, Ta, Tv);
  loss_kernel<<<NOUT / 8, 256, 0, stream>>>(Ta, Tv, pred_a, pred_v, perm_idx,
                                            cls_idx, out);
}

// Round 14
// 71.630 us; speedup vs baseline: 1.3349x; 1.1521x over previous
//
#include <hip/hip_runtime.h>
#include <hip/hip_bf16.h>
#include <math.h>

// Problem constants
#define S 64
#define F 10
#define K 7
#define D 512
#define HH 196   // H*H = 14*14
#define DT 128
#define NF (S*F)          // 640
#define NROWS_V (S*F*K)   // 4480
#define NROWS_A (S*K)     // 448
#define NOUT (S*K*F)      // 4480
#define MLP_BLK_A (NROWS_A / 16)   // 28
#define MLP_BLK_V (NROWS_V / 16)   // 280

typedef short bf16x8 __attribute__((ext_vector_type(8)));
typedef float f32x4 __attribute__((ext_vector_type(4)));

__device__ __forceinline__ unsigned short bfc(float x) {
  __hip_bfloat16 h = __float2bfloat16(x);
  return *reinterpret_cast<unsigned short*>(&h);
}

// ---------------------------------------------------------------------------
// conv_kernel: one-shot input conversions for the MFMA MLP.
// seg0: feat_a f32 -> bf16 (linear).  seg1/2: W1{a,v}[512x128] -> W1T[128x512]
// bf16.  seg3/4: W2{a,v}[128x128] -> W2T[128x128] bf16. Writes coalesced,
// reads strided (tiny, L2-absorbed).
// ---------------------------------------------------------------------------
__global__ __launch_bounds__(256) void conv_kernel(
    const float* __restrict__ feat_a,
    const float* __restrict__ W1a, const float* __restrict__ W1v,
    const float* __restrict__ W2a, const float* __restrict__ W2v,
    unsigned short* __restrict__ XaB,
    unsigned short* __restrict__ W1aT, unsigned short* __restrict__ W1vT,
    unsigned short* __restrict__ W2aT, unsigned short* __restrict__ W2vT) {
  const int b = blockIdx.x;
  const int t = threadIdx.x;
  if (b < 224) {  // feat_a: 57344 float4
    const int o = b * 256 + t;
    const float4 v = reinterpret_cast<const float4*>(feat_a)[o];
    unsigned short s0 = bfc(v.x), s1 = bfc(v.y), s2 = bfc(v.z), s3 = bfc(v.w);
    uint2 pk;
    pk.x = ((unsigned)s1 << 16) | s0;
    pk.y = ((unsigned)s3 << 16) | s2;
    reinterpret_cast<uint2*>(XaB)[o] = pk;
  } else if (b < 480) {  // W1a transpose: 65536 elems
    const int o = (b - 224) * 256 + t;
    const int j = o >> 9, d = o & 511;
    W1aT[o] = bfc(W1a[d * DT + j]);
  } else if (b < 736) {  // W1v transpose
    const int o = (b - 480) * 256 + t;
    const int j = o >> 9, d = o & 511;
    W1vT[o] = bfc(W1v[d * DT + j]);
  } else if (b < 800) {  // W2a transpose: 16384 elems
    const int o = (b - 736) * 256 + t;
    const int j = o >> 7, d = o & 127;
    W2aT[o] = bfc(W2a[d * DT + j]);
  } else {               // W2v transpose
    const int o = (b - 800) * 256 + t;
    const int j = o >> 7, d = o & 127;
    W2vT[o] = bfc(W2v[d * DT + j]);
  }
}

// ---------------------------------------------------------------------------
// Kernel 1 (v10, MFMA): identical math to R13's v9, but writes fg as BF16
// (mlp3's A operand; halves write traffic). Conventions HW-validated R11/R13
// (absmax 6e-5).
// ---------------------------------------------------------------------------
__global__ __launch_bounds__(256) void fg_kernel(
    const float* __restrict__ feat, const float* __restrict__ cam,
    unsigned short* __restrict__ fgb) {
  const int t = threadIdx.x;
  const int lane = t & 63;
  const int w = t >> 6;
  const int col = lane & 15;
  const int kg = lane >> 4;
  const int n = blockIdx.x >> 1;
  const int half = blockIdx.x & 1;
  const int c0blk = half * 256;

  const float* featn = feat + ((size_t)n * D + c0blk) * HH;
  const float* camn = cam + (size_t)n * K * HH;

  bf16x8 bs[7];
  {
    const float* crow = camn + col * HH;
#pragma unroll
    for (int s = 0; s < 7; ++s) {
      float v0 = 0.f, v1 = 0.f, v2 = 0.f, v3 = 0.f;
      float v4 = 0.f, v5 = 0.f, v6 = 0.f, v7 = 0.f;
      if (col < 7) {
        if (s < 6) {
          const float4 lo = *reinterpret_cast<const float4*>(crow + s * 32 + kg * 8);
          const float4 hi = *reinterpret_cast<const float4*>(crow + s * 32 + kg * 8 + 4);
          v0 = lo.x; v1 = lo.y; v2 = lo.z; v3 = lo.w;
          v4 = hi.x; v5 = hi.y; v6 = hi.z; v7 = hi.w;
        } else if (kg == 0) {
          const float4 lo = *reinterpret_cast<const float4*>(crow + 192);
          v0 = lo.x; v1 = lo.y; v2 = lo.z; v3 = lo.w;
        }
      }
      bs[s][0] = bfc(v0); bs[s][1] = bfc(v1); bs[s][2] = bfc(v2); bs[s][3] = bfc(v3);
      bs[s][4] = bfc(v4); bs[s][5] = bfc(v5); bs[s][6] = bfc(v6); bs[s][7] = bfc(v7);
    }
  }

  float invc = 0.f;
#pragma unroll
  for (int k = 0; k < K; ++k) {
    float4 cv = (lane < 49)
                    ? *reinterpret_cast<const float4*>(camn + k * HH + 4 * lane)
                    : make_float4(0.f, 0.f, 0.f, 0.f);
    float s = cv.x + cv.y + cv.z + cv.w;
#pragma unroll
    for (int m = 32; m >= 1; m >>= 1) s += __shfl_xor(s, m, 64);
    const float iv = 1.0f / (s + 1e-10f);
    if (col == k) invc = iv;
  }

  unsigned short* fgn = fgb + (size_t)n * K * D;

#pragma unroll
  for (int mt = 0; mt < 4; ++mt) {
    const int chl = (w * 4 + mt) * 16 + col;
    const float* rowp = featn + (size_t)chl * HH;

    f32x4 acc = {0.f, 0.f, 0.f, 0.f};
#pragma unroll
    for (int s = 0; s < 7; ++s) {
      float v0 = 0.f, v1 = 0.f, v2 = 0.f, v3 = 0.f;
      float v4 = 0.f, v5 = 0.f, v6 = 0.f, v7 = 0.f;
      if (s < 6) {
        const float4 lo = *reinterpret_cast<const float4*>(rowp + s * 32 + kg * 8);
        const float4 hi = *reinterpret_cast<const float4*>(rowp + s * 32 + kg * 8 + 4);
        v0 = lo.x; v1 = lo.y; v2 = lo.z; v3 = lo.w;
        v4 = hi.x; v5 = hi.y; v6 = hi.z; v7 = hi.w;
      } else if (kg == 0) {
        const float4 lo = *reinterpret_cast<const float4*>(rowp + 192);
        v0 = lo.x; v1 = lo.y; v2 = lo.z; v3 = lo.w;
      }
      bf16x8 a;
      a[0] = bfc(v0); a[1] = bfc(v1); a[2] = bfc(v2); a[3] = bfc(v3);
      a[4] = bfc(v4); a[5] = bfc(v5); a[6] = bfc(v6); a[7] = bfc(v7);
      acc = __builtin_amdgcn_mfma_f32_16x16x32_bf16(a, bs[s], acc, 0, 0, 0);
    }

    if (col < 7) {
      uint2 pk;
      pk.x = ((unsigned)bfc(acc[1] * invc) << 16) | bfc(acc[0] * invc);
      pk.y = ((unsigned)bfc(acc[3] * invc) << 16) | bfc(acc[2] * invc);
      *reinterpret_cast<uint2*>(
          fgn + (size_t)col * D + c0blk + (w * 4 + mt) * 16 + kg * 4) = pk;
    }
  }
}

// ---------------------------------------------------------------------------
// Kernel 2 (mlp3, MFMA): per block, 16 rows x 128 cols of
//   T = (relu(X W1 + b1) W2 + b2) * g + bn
// 4 waves; wave w owns cols [w*32, w*32+32) (2 n-tiles). Layer 1: K=512 in
// 16 slabs; A-frags straight from global bf16 X (16 fully-consumed lines per
// instr; waves share via L1), B from pre-transposed W1T. h (bf16) passes
// through a padded LDS tile [16][144] (stride 288 B: 16B-aligned, <=4-way
// bank conflicts) -- ONE barrier -- then layer 2 (4 slabs) vs W2T.
// C/D mapping per fg-validated convention.
// ---------------------------------------------------------------------------
__global__ __launch_bounds__(256) void mlp3_kernel(
    const unsigned short* __restrict__ XaB, const unsigned short* __restrict__ XvB,
    const unsigned short* __restrict__ W1aT, const unsigned short* __restrict__ W2aT,
    const float* __restrict__ b1a, const float* __restrict__ b2a,
    const float* __restrict__ ga, const float* __restrict__ bna,
    const unsigned short* __restrict__ W1vT, const unsigned short* __restrict__ W2vT,
    const float* __restrict__ b1v, const float* __restrict__ b2v,
    const float* __restrict__ gv, const float* __restrict__ bnv,
    float* __restrict__ Ta, float* __restrict__ Tv) {
  __shared__ unsigned short hs[16 * 144];   // 4608 B, padded stride 144

  const int t = threadIdx.x;
  const int lane = t & 63;
  const int w = t >> 6;
  const int c15 = lane & 15;
  const int kg = lane >> 4;
  const int nbase = w * 32;
  const int b = blockIdx.x;

  const unsigned short *XB, *W1T, *W2T;
  const float *b1, *b2, *g, *bn;
  float* out;
  int r0;
  if (b < MLP_BLK_A) {
    XB = XaB; W1T = W1aT; W2T = W2aT; b1 = b1a; b2 = b2a; g = ga; bn = bna;
    out = Ta; r0 = b * 16;
  } else {
    XB = XvB; W1T = W1vT; W2T = W2vT; b1 = b1v; b2 = b2v; g = gv; bn = bnv;
    out = Tv; r0 = (b - MLP_BLK_A) * 16;
  }

  // ---- layer 1: 16 k-slabs of 32 ----
  const unsigned short* xp = XB + (size_t)(r0 + c15) * D + kg * 8;
  const unsigned short* wp0 = W1T + (size_t)(nbase + c15) * D + kg * 8;
  const unsigned short* wp1 = W1T + (size_t)(nbase + 16 + c15) * D + kg * 8;

  f32x4 acc0 = {0.f, 0.f, 0.f, 0.f};
  f32x4 acc1 = {0.f, 0.f, 0.f, 0.f};
#pragma unroll
  for (int s = 0; s < 16; ++s) {
    const bf16x8 a = *reinterpret_cast<const bf16x8*>(xp + s * 32);
    const bf16x8 w0 = *reinterpret_cast<const bf16x8*>(wp0 + s * 32);
    const bf16x8 w1 = *reinterpret_cast<const bf16x8*>(wp1 + s * 32);
    acc0 = __builtin_amdgcn_mfma_f32_16x16x32_bf16(a, w0, acc0, 0, 0, 0);
    acc1 = __builtin_amdgcn_mfma_f32_16x16x32_bf16(a, w1, acc1, 0, 0, 0);
  }

  // bias + relu -> hs (bf16). lane holds rows kg*4+i at cols nbase+c15 (+16).
  {
    const float bc0 = b1[nbase + c15];
    const float bc1 = b1[nbase + 16 + c15];
#pragma unroll
    for (int i = 0; i < 4; ++i) {
      const int row = kg * 4 + i;
      hs[row * 144 + nbase + c15] = bfc(fmaxf(acc0[i] + bc0, 0.f));
      hs[row * 144 + nbase + 16 + c15] = bfc(fmaxf(acc1[i] + bc1, 0.f));
    }
  }
  __syncthreads();

  // ---- layer 2: 4 k-slabs of 32 over h[16][128] ----
  const unsigned short* w2p0 = W2T + (size_t)(nbase + c15) * DT + kg * 8;
  const unsigned short* w2p1 = W2T + (size_t)(nbase + 16 + c15) * DT + kg * 8;
  f32x4 c0 = {0.f, 0.f, 0.f, 0.f};
  f32x4 c1 = {0.f, 0.f, 0.f, 0.f};
#pragma unroll
  for (int s = 0; s < 4; ++s) {
    const bf16x8 a = *reinterpret_cast<const bf16x8*>(hs + c15 * 144 + s * 32 + kg * 8);
    const bf16x8 w0 = *reinterpret_cast<const bf16x8*>(w2p0 + s * 32);
    const bf16x8 w1 = *reinterpret_cast<const bf16x8*>(w2p1 + s * 32);
    c0 = __builtin_amdgcn_mfma_f32_16x16x32_bf16(a, w0, c0, 0, 0, 0);
    c1 = __builtin_amdgcn_mfma_f32_16x16x32_bf16(a, w1, c1, 0, 0, 0);
  }

  // epilogue: (y + b2) * g + bn, f32 out
  {
    const int col0 = nbase + c15;
    const int col1 = nbase + 16 + c15;
    const float b20 = b2[col0], b21 = b2[col1];
    const float g0 = g[col0], g1 = g[col1];
    const float n0 = bn[col0], n1 = bn[col1];
#pragma unroll
    for (int i = 0; i < 4; ++i) {
      const int row = r0 + kg * 4 + i;
      out[(size_t)row * DT + col0] = (c0[i] + b20) * g0 + n0;
      out[(size_t)row * DT + col1] = (c1[i] + b21) * g1 + n1;
    }
  }
}

// ---------------------------------------------------------------------------
// Kernel 3: losses + masks (unchanged; ~0.85 us).
// ---------------------------------------------------------------------------
__global__ __launch_bounds__(256) void loss_kernel(
    const float* __restrict__ Ta, const float* __restrict__ Tv,
    const float* __restrict__ pred_a, const float* __restrict__ pred_v,
    const int* __restrict__ perm_idx, const int* __restrict__ cls_idx,
    float* __restrict__ out) {
  const int t = threadIdx.x;
  const int sub = t & 31;
  const int idx = blockIdx.x * 8 + (t >> 5);
  const int f = idx % F;
  const int k = (idx / F) % K;
  const int s = idx / (K * F);

  const int p = perm_idx[idx];
  const int c = cls_idx[idx];
  const int rowd = ((s ^ 1) * F + p) * K + c;

  float4 ta = reinterpret_cast<const float4*>(Ta)[(s * K + k) * 32 + sub];
  float4 tv = reinterpret_cast<const float4*>(Tv)[((s * F + f) * K + k) * 32 + sub];
  float4 td = reinterpret_cast<const float4*>(Tv)[rowd * 32 + sub];
  float d1 = 0.f, d2 = 0.f, e;
  e = ta.x - tv.x; d1 += e * e;
  e = ta.y - tv.y; d1 += e * e;
  e = ta.z - tv.z; d1 += e * e;
  e = ta.w - tv.w; d1 += e * e;
  e = ta.x - td.x; d2 += e * e;
  e = ta.y - td.y; d2 += e * e;
  e = ta.z - td.z; d2 += e * e;
  e = ta.w - td.w; d2 += e * e;
#pragma unroll
  for (int m = 16; m >= 1; m >>= 1) {
    d1 += __shfl_xor(d1, m, 64);
    d2 += __shfl_xor(d2, m, 64);
  }
  if (sub == 0) {
    float pa = pred_a[s * K + k];
    bool act = pa > 0.3f;
    int num = (int)floorf(pa * (float)F);
    float pvv = pred_v[(s * F + f) * K + k];
    float sg = 1.0f / (1.0f + expf(-pvv));
    bool mco = act && (sg > 0.3f);
    bool mdi = act && (f < num);
    float lco = d1 * (1.0f / 128.0f);
    float ldi = d2 * (1.0f / 128.0f);
    out[idx] = mco ? lco : 0.0f;
    out[NOUT + idx] = mdi ? ldi : 0.0f;
    out[2 * NOUT + idx] = mco ? 1.0f : 0.0f;
    out[3 * NOUT + idx] = mdi ? 1.0f : 0.0f;
  }
}

extern "C" void kernel_launch(void* const* d_in, const int* in_sizes, int n_in,
                              void* d_out, int out_size, void* d_ws, size_t ws_size,
                              hipStream_t stream) {
  const float* feat_a     = (const float*)d_in[0];
  const float* pred_a     = (const float*)d_in[1];
  const float* feat_v_raw = (const float*)d_in[2];
  const float* pred_v     = (const float*)d_in[3];
  const float* cam        = (const float*)d_in[4];
  const float* W1a = (const float*)d_in[5];
  const float* b1a = (const float*)d_in[6];
  const float* W2a = (const float*)d_in[7];
  const float* b2a = (const float*)d_in[8];
  const float* ga  = (const float*)d_in[9];
  const float* bna = (const float*)d_in[10];
  const float* W1v = (const float*)d_in[11];
  const float* b1v = (const float*)d_in[12];
  const float* W2v = (const float*)d_in[13];
  const float* b2v = (const float*)d_in[14];
  const float* gv  = (const float*)d_in[15];
  const float* bnv = (const float*)d_in[16];
  const int* perm_idx = (const int*)d_in[17];
  const int* cls_idx  = (const int*)d_in[18];
  float* out = (float*)d_out;

  // workspace layout (bytes):
  // fgb 4,587,520 | XaB 458,752 | W1aT 131,072 | W1vT 131,072 |
  // W2aT 32,768 | W2vT 32,768 | Ta 229,376 | Tv 2,293,760
  char* w = (char*)d_ws;
  unsigned short* fgb  = (unsigned short*)(w);
  unsigned short* XaB  = (unsigned short*)(w + 4587520);
  unsigned short* W1aT = (unsigned short*)(w + 4587520 + 458752);
  unsigned short* W1vT = (unsigned short*)(w + 4587520 + 458752 + 131072);
  unsigned short* W2aT = (unsigned short*)(w + 4587520 + 458752 + 262144);
  unsigned short* W2vT = (unsigned short*)(w + 4587520 + 458752 + 262144 + 32768);
  float* Ta = (float*)(w + 4587520 + 458752 + 262144 + 65536);
  float* Tv = (float*)(w + 4587520 + 458752 + 262144 + 65536 + 229376);

  conv_kernel<<<864, 256, 0, stream>>>(feat_a, W1a, W1v, W2a, W2v,
                                       XaB, W1aT, W1vT, W2aT, W2vT);
  fg_kernel<<<NF * 2, 256, 0, stream>>>(feat_v_raw, cam, fgb);
  mlp3_kernel<<<MLP_BLK_A + MLP_BLK_V, 256, 0, stream>>>(
      XaB, fgb, W1aT, W2aT, b1a, b2a, ga, bna,
      W1vT, W2vT, b1v, b2v, gv, bnv, Ta, Tv);
  loss_kernel<<<NOUT / 8, 256, 0, stream>>>(Ta, Tv, pred_a, pred_v, perm_idx,
                                            cls_idx, out);
}

// Round 15
// 67.055 us; speedup vs baseline: 1.4259x; 1.0682x over previous
//
#include <hip/hip_runtime.h>
#include <hip/hip_bf16.h>
#include <math.h>

// Problem constants
#define S 64
#define F 10
#define K 7
#define D 512
#define HH 196   // H*H = 14*14
#define DT 128
#define NF (S*F)          // 640
#define NROWS_V (S*F*K)   // 4480
#define NROWS_A (S*K)     // 448
#define NOUT (S*K*F)      // 4480
#define MLP_BLK_A (NROWS_A / 16)   // 28
#define MLP_BLK_V (NROWS_V / 16)   // 280
#define FG_BLKS (NF * 2)           // 1280
#define CONV_BLKS 864

typedef short bf16x8 __attribute__((ext_vector_type(8)));
typedef float f32x4 __attribute__((ext_vector_type(4)));

__device__ __forceinline__ unsigned short bfc(float x) {
  __hip_bfloat16 h = __float2bfloat16(x);
  return *reinterpret_cast<unsigned short*>(&h);
}

// ---------------------------------------------------------------------------
// Kernel 1 (v11): fused fg-MFMA + input-conversion dispatch.
// Blocks [0,1280): fg = per-n C[512x7] = feat[512x196] x cam^T[196x7] via
//   mfma_f32_16x16x32_bf16 (conventions HW-validated R11/R13, absmax 6e-5);
//   output written as bf16 (mlp3 A operand).
// Blocks [1280,2144): conv = feat_a f32->bf16 and W1/W2 -> transposed bf16.
//   conv backfills CUs while fg streams (fg is HBM-bound; conv rides free).
// No LDS in either path; fg path dominates VGPR -> occupancy unchanged.
// ---------------------------------------------------------------------------
__global__ __launch_bounds__(256) void fgconv_kernel(
    const float* __restrict__ feat, const float* __restrict__ cam,
    unsigned short* __restrict__ fgb,
    const float* __restrict__ feat_a,
    const float* __restrict__ W1a, const float* __restrict__ W1v,
    const float* __restrict__ W2a, const float* __restrict__ W2v,
    unsigned short* __restrict__ XaB,
    unsigned short* __restrict__ W1aT, unsigned short* __restrict__ W1vT,
    unsigned short* __restrict__ W2aT, unsigned short* __restrict__ W2vT) {
  const int t = threadIdx.x;

  if (blockIdx.x >= FG_BLKS) {
    // ---------------- conv path ----------------
    const int b = blockIdx.x - FG_BLKS;
    if (b < 224) {  // feat_a: 57344 float4
      const int o = b * 256 + t;
      const float4 v = reinterpret_cast<const float4*>(feat_a)[o];
      unsigned short s0 = bfc(v.x), s1 = bfc(v.y), s2 = bfc(v.z), s3 = bfc(v.w);
      uint2 pk;
      pk.x = ((unsigned)s1 << 16) | s0;
      pk.y = ((unsigned)s3 << 16) | s2;
      reinterpret_cast<uint2*>(XaB)[o] = pk;
    } else if (b < 480) {  // W1a transpose: 65536 elems
      const int o = (b - 224) * 256 + t;
      const int j = o >> 9, d = o & 511;
      W1aT[o] = bfc(W1a[d * DT + j]);
    } else if (b < 736) {  // W1v transpose
      const int o = (b - 480) * 256 + t;
      const int j = o >> 9, d = o & 511;
      W1vT[o] = bfc(W1v[d * DT + j]);
    } else if (b < 800) {  // W2a transpose: 16384 elems
      const int o = (b - 736) * 256 + t;
      const int j = o >> 7, d = o & 127;
      W2aT[o] = bfc(W2a[d * DT + j]);
    } else {               // W2v transpose
      const int o = (b - 800) * 256 + t;
      const int j = o >> 7, d = o & 127;
      W2vT[o] = bfc(W2v[d * DT + j]);
    }
    return;
  }

  // ---------------- fg path ----------------
  const int lane = t & 63;
  const int w = t >> 6;
  const int col = lane & 15;
  const int kg = lane >> 4;
  const int n = blockIdx.x >> 1;
  const int half = blockIdx.x & 1;
  const int c0blk = half * 256;

  const float* featn = feat + ((size_t)n * D + c0blk) * HH;
  const float* camn = cam + (size_t)n * K * HH;

  bf16x8 bs[7];
  {
    const float* crow = camn + col * HH;
#pragma unroll
    for (int s = 0; s < 7; ++s) {
      float v0 = 0.f, v1 = 0.f, v2 = 0.f, v3 = 0.f;
      float v4 = 0.f, v5 = 0.f, v6 = 0.f, v7 = 0.f;
      if (col < 7) {
        if (s < 6) {
          const float4 lo = *reinterpret_cast<const float4*>(crow + s * 32 + kg * 8);
          const float4 hi = *reinterpret_cast<const float4*>(crow + s * 32 + kg * 8 + 4);
          v0 = lo.x; v1 = lo.y; v2 = lo.z; v3 = lo.w;
          v4 = hi.x; v5 = hi.y; v6 = hi.z; v7 = hi.w;
        } else if (kg == 0) {
          const float4 lo = *reinterpret_cast<const float4*>(crow + 192);
          v0 = lo.x; v1 = lo.y; v2 = lo.z; v3 = lo.w;
        }
      }
      bs[s][0] = bfc(v0); bs[s][1] = bfc(v1); bs[s][2] = bfc(v2); bs[s][3] = bfc(v3);
      bs[s][4] = bfc(v4); bs[s][5] = bfc(v5); bs[s][6] = bfc(v6); bs[s][7] = bfc(v7);
    }
  }

  float invc = 0.f;
#pragma unroll
  for (int k = 0; k < K; ++k) {
    float4 cv = (lane < 49)
                    ? *reinterpret_cast<const float4*>(camn + k * HH + 4 * lane)
                    : make_float4(0.f, 0.f, 0.f, 0.f);
    float s = cv.x + cv.y + cv.z + cv.w;
#pragma unroll
    for (int m = 32; m >= 1; m >>= 1) s += __shfl_xor(s, m, 64);
    const float iv = 1.0f / (s + 1e-10f);
    if (col == k) invc = iv;
  }

  unsigned short* fgn = fgb + (size_t)n * K * D;

#pragma unroll
  for (int mt = 0; mt < 4; ++mt) {
    const int chl = (w * 4 + mt) * 16 + col;
    const float* rowp = featn + (size_t)chl * HH;

    f32x4 acc = {0.f, 0.f, 0.f, 0.f};
#pragma unroll
    for (int s = 0; s < 7; ++s) {
      float v0 = 0.f, v1 = 0.f, v2 = 0.f, v3 = 0.f;
      float v4 = 0.f, v5 = 0.f, v6 = 0.f, v7 = 0.f;
      if (s < 6) {
        const float4 lo = *reinterpret_cast<const float4*>(rowp + s * 32 + kg * 8);
        const float4 hi = *reinterpret_cast<const float4*>(rowp + s * 32 + kg * 8 + 4);
        v0 = lo.x; v1 = lo.y; v2 = lo.z; v3 = lo.w;
        v4 = hi.x; v5 = hi.y; v6 = hi.z; v7 = hi.w;
      } else if (kg == 0) {
        const float4 lo = *reinterpret_cast<const float4*>(rowp + 192);
        v0 = lo.x; v1 = lo.y; v2 = lo.z; v3 = lo.w;
      }
      bf16x8 a;
      a[0] = bfc(v0); a[1] = bfc(v1); a[2] = bfc(v2); a[3] = bfc(v3);
      a[4] = bfc(v4); a[5] = bfc(v5); a[6] = bfc(v6); a[7] = bfc(v7);
      acc = __builtin_amdgcn_mfma_f32_16x16x32_bf16(a, bs[s], acc, 0, 0, 0);
    }

    if (col < 7) {
      uint2 pk;
      pk.x = ((unsigned)bfc(acc[1] * invc) << 16) | bfc(acc[0] * invc);
      pk.y = ((unsigned)bfc(acc[3] * invc) << 16) | bfc(acc[2] * invc);
      *reinterpret_cast<uint2*>(
          fgn + (size_t)col * D + c0blk + (w * 4 + mt) * 16 + kg * 4) = pk;
    }
  }
}

// ---------------------------------------------------------------------------
// Kernel 2 (mlp3, MFMA, R14-validated): 16 rows x 128 cols per block, layer1
// 16 k-slabs from global bf16 X / W1T, h through padded LDS (one barrier),
// layer2 4 k-slabs vs W2T, fused bias+relu+affine epilogue.
// ---------------------------------------------------------------------------
__global__ __launch_bounds__(256) void mlp3_kernel(
    const unsigned short* __restrict__ XaB, const unsigned short* __restrict__ XvB,
    const unsigned short* __restrict__ W1aT, const unsigned short* __restrict__ W2aT,
    const float* __restrict__ b1a, const float* __restrict__ b2a,
    const float* __restrict__ ga, const float* __restrict__ bna,
    const unsigned short* __restrict__ W1vT, const unsigned short* __restrict__ W2vT,
    const float* __restrict__ b1v, const float* __restrict__ b2v,
    const float* __restrict__ gv, const float* __restrict__ bnv,
    float* __restrict__ Ta, float* __restrict__ Tv) {
  __shared__ unsigned short hs[16 * 144];   // 4608 B, padded stride 144

  const int t = threadIdx.x;
  const int lane = t & 63;
  const int w = t >> 6;
  const int c15 = lane & 15;
  const int kg = lane >> 4;
  const int nbase = w * 32;
  const int b = blockIdx.x;

  const unsigned short *XB, *W1T, *W2T;
  const float *b1, *b2, *g, *bn;
  float* out;
  int r0;
  if (b < MLP_BLK_A) {
    XB = XaB; W1T = W1aT; W2T = W2aT; b1 = b1a; b2 = b2a; g = ga; bn = bna;
    out = Ta; r0 = b * 16;
  } else {
    XB = XvB; W1T = W1vT; W2T = W2vT; b1 = b1v; b2 = b2v; g = gv; bn = bnv;
    out = Tv; r0 = (b - MLP_BLK_A) * 16;
  }

  const unsigned short* xp = XB + (size_t)(r0 + c15) * D + kg * 8;
  const unsigned short* wp0 = W1T + (size_t)(nbase + c15) * D + kg * 8;
  const unsigned short* wp1 = W1T + (size_t)(nbase + 16 + c15) * D + kg * 8;

  f32x4 acc0 = {0.f, 0.f, 0.f, 0.f};
  f32x4 acc1 = {0.f, 0.f, 0.f, 0.f};
#pragma unroll
  for (int s = 0; s < 16; ++s) {
    const bf16x8 a = *reinterpret_cast<const bf16x8*>(xp + s * 32);
    const bf16x8 w0 = *reinterpret_cast<const bf16x8*>(wp0 + s * 32);
    const bf16x8 w1 = *reinterpret_cast<const bf16x8*>(wp1 + s * 32);
    acc0 = __builtin_amdgcn_mfma_f32_16x16x32_bf16(a, w0, acc0, 0, 0, 0);
    acc1 = __builtin_amdgcn_mfma_f32_16x16x32_bf16(a, w1, acc1, 0, 0, 0);
  }

  {
    const float bc0 = b1[nbase + c15];
    const float bc1 = b1[nbase + 16 + c15];
#pragma unroll
    for (int i = 0; i < 4; ++i) {
      const int row = kg * 4 + i;
      hs[row * 144 + nbase + c15] = bfc(fmaxf(acc0[i] + bc0, 0.f));
      hs[row * 144 + nbase + 16 + c15] = bfc(fmaxf(acc1[i] + bc1, 0.f));
    }
  }
  __syncthreads();

  const unsigned short* w2p0 = W2T + (size_t)(nbase + c15) * DT + kg * 8;
  const unsigned short* w2p1 = W2T + (size_t)(nbase + 16 + c15) * DT + kg * 8;
  f32x4 c0 = {0.f, 0.f, 0.f, 0.f};
  f32x4 c1 = {0.f, 0.f, 0.f, 0.f};
#pragma unroll
  for (int s = 0; s < 4; ++s) {
    const bf16x8 a = *reinterpret_cast<const bf16x8*>(hs + c15 * 144 + s * 32 + kg * 8);
    const bf16x8 w0 = *reinterpret_cast<const bf16x8*>(w2p0 + s * 32);
    const bf16x8 w1 = *reinterpret_cast<const bf16x8*>(w2p1 + s * 32);
    c0 = __builtin_amdgcn_mfma_f32_16x16x32_bf16(a, w0, c0, 0, 0, 0);
    c1 = __builtin_amdgcn_mfma_f32_16x16x32_bf16(a, w1, c1, 0, 0, 0);
  }

  {
    const int col0 = nbase + c15;
    const int col1 = nbase + 16 + c15;
    const float b20 = b2[col0], b21 = b2[col1];
    const float g0 = g[col0], g1 = g[col1];
    const float n0 = bn[col0], n1 = bn[col1];
#pragma unroll
    for (int i = 0; i < 4; ++i) {
      const int row = r0 + kg * 4 + i;
      out[(size_t)row * DT + col0] = (c0[i] + b20) * g0 + n0;
      out[(size_t)row * DT + col1] = (c1[i] + b21) * g1 + n1;
    }
  }
}

// ---------------------------------------------------------------------------
// Kernel 3: losses + masks (unchanged; ~0.85 us).
// ---------------------------------------------------------------------------
__global__ __launch_bounds__(256) void loss_kernel(
    const float* __restrict__ Ta, const float* __restrict__ Tv,
    const float* __restrict__ pred_a, const float* __restrict__ pred_v,
    const int* __restrict__ perm_idx, const int* __restrict__ cls_idx,
    float* __restrict__ out) {
  const int t = threadIdx.x;
  const int sub = t & 31;
  const int idx = blockIdx.x * 8 + (t >> 5);
  const int f = idx % F;
  const int k = (idx / F) % K;
  const int s = idx / (K * F);

  const int p = perm_idx[idx];
  const int c = cls_idx[idx];
  const int rowd = ((s ^ 1) * F + p) * K + c;

  float4 ta = reinterpret_cast<const float4*>(Ta)[(s * K + k) * 32 + sub];
  float4 tv = reinterpret_cast<const float4*>(Tv)[((s * F + f) * K + k) * 32 + sub];
  float4 td = reinterpret_cast<const float4*>(Tv)[rowd * 32 + sub];
  float d1 = 0.f, d2 = 0.f, e;
  e = ta.x - tv.x; d1 += e * e;
  e = ta.y - tv.y; d1 += e * e;
  e = ta.z - tv.z; d1 += e * e;
  e = ta.w - tv.w; d1 += e * e;
  e = ta.x - td.x; d2 += e * e;
  e = ta.y - td.y; d2 += e * e;
  e = ta.z - td.z; d2 += e * e;
  e = ta.w - td.w; d2 += e * e;
#pragma unroll
  for (int m = 16; m >= 1; m >>= 1) {
    d1 += __shfl_xor(d1, m, 64);
    d2 += __shfl_xor(d2, m, 64);
  }
  if (sub == 0) {
    float pa = pred_a[s * K + k];
    bool act = pa > 0.3f;
    int num = (int)floorf(pa * (float)F);
    float pvv = pred_v[(s * F + f) * K + k];
    float sg = 1.0f / (1.0f + expf(-pvv));
    bool mco = act && (sg > 0.3f);
    bool mdi = act && (f < num);
    float lco = d1 * (1.0f / 128.0f);
    float ldi = d2 * (1.0f / 128.0f);
    out[idx] = mco ? lco : 0.0f;
    out[NOUT + idx] = mdi ? ldi : 0.0f;
    out[2 * NOUT + idx] = mco ? 1.0f : 0.0f;
    out[3 * NOUT + idx] = mdi ? 1.0f : 0.0f;
  }
}

extern "C" void kernel_launch(void* const* d_in, const int* in_sizes, int n_in,
                              void* d_out, int out_size, void* d_ws, size_t ws_size,
                              hipStream_t stream) {
  const float* feat_a     = (const float*)d_in[0];
  const float* pred_a     = (const float*)d_in[1];
  const float* feat_v_raw = (const float*)d_in[2];
  const float* pred_v     = (const float*)d_in[3];
  const float* cam        = (const float*)d_in[4];
  const float* W1a = (const float*)d_in[5];
  const float* b1a = (const float*)d_in[6];
  const float* W2a = (const float*)d_in[7];
  const float* b2a = (const float*)d_in[8];
  const float* ga  = (const float*)d_in[9];
  const float* bna = (const float*)d_in[10];
  const float* W1v = (const float*)d_in[11];
  const float* b1v = (const float*)d_in[12];
  const float* W2v = (const float*)d_in[13];
  const float* b2v = (const float*)d_in[14];
  const float* gv  = (const float*)d_in[15];
  const float* bnv = (const float*)d_in[16];
  const int* perm_idx = (const int*)d_in[17];
  const int* cls_idx  = (const int*)d_in[18];
  float* out = (float*)d_out;

  // workspace layout (bytes):
  // fgb 4,587,520 | XaB 458,752 | W1aT 131,072 | W1vT 131,072 |
  // W2aT 32,768 | W2vT 32,768 | Ta 229,376 | Tv 2,293,760
  char* w = (char*)d_ws;
  unsigned short* fgb  = (unsigned short*)(w);
  unsigned short* XaB  = (unsigned short*)(w + 4587520);
  unsigned short* W1aT = (unsigned short*)(w + 4587520 + 458752);
  unsigned short* W1vT = (unsigned short*)(w + 4587520 + 458752 + 131072);
  unsigned short* W2aT = (unsigned short*)(w + 4587520 + 458752 + 262144);
  unsigned short* W2vT = (unsigned short*)(w + 4587520 + 458752 + 262144 + 32768);
  float* Ta = (float*)(w + 4587520 + 458752 + 262144 + 65536);
  float* Tv = (float*)(w + 4587520 + 458752 + 262144 + 65536 + 229376);

  fgconv_kernel<<<FG_BLKS + CONV_BLKS, 256, 0, stream>>>(
      feat_v_raw, cam, fgb, feat_a, W1a, W1v, W2a, W2v,
      XaB, W1aT, W1vT, W2aT, W2vT);
  mlp3_kernel<<<MLP_BLK_A + MLP_BLK_V, 256, 0, stream>>>(
      XaB, fgb, W1aT, W2aT, b1a, b2a, ga, bna,
      W1vT, W2vT, b1v, b2v, gv, bnv, Ta, Tv);
  loss_kernel<<<NOUT / 8, 256, 0, stream>>>(Ta, Tv, pred_a, pred_v, perm_idx,
                                            cls_idx, out);
}